// Round 6
// baseline (229.704 us; speedup 1.0000x reference)
//
#include <hip/hip_runtime.h>
#include <cstdint>

// ===========================================================================
// KWS_LSTM_bmm — exact integer reformulation, fp32-faithful quant decisions.
// R20: DPP-dedup h-reads. R19 (gate-pipelining) was null -> compiler already
//   schedules optimally; attack LDS instruction count instead.
//   h-fragment reads were HALF-DENSE: lanes 2k,2k+1 need identical 16B
//   (arow=c>>1 dup), so 4 ds_read_b128/wave moved only 512 unique B each.
//   Now: pair chunks (1,2) and (3,4); lane l fetches chunk m0+(l&1) for its
//   (row,q) -> 1 FULL-DENSITY b128 per pair (64 distinct addrs, 8/bank =
//   BW floor); 16 v_mov_dpp quad_perm ([0,0,2,2] even->all, [1,1,3,3]
//   odd->all) rebuild all 4 fragments per lane on the VALU pipe.
//   LDS h-read instrs 52 -> 26 per CU-step; bit-identical MFMA operands.
//   Kept: R19 gate-chain structure, pre-barrier x prefetch, fixed acc regs
//   0/2, float tanc[255], 1 barrier/step, 13 waves, 128 regs/wave.
// Exactness: every lattice chain bit-exact in fp32 (numerators < 2^24);
// sigmoid/tanh exact byte LUTs (fast fp32 + 0.498-margin fp64 fallback).
// ===========================================================================

typedef int v4i __attribute__((ext_vector_type(4)));

#define SEQn 101
#define BLK  832              // 13 waves
#define HST  288              // h row stride (bank-optimal paired b128 reads)
#define HSLOT 2304            // 8 rows
#define SIG_OFF 22720
#define SIG_SZ  41152         // sigmoid q-LUT (idx >= 41152 saturates to 127)
#define TMAX 10527            // |tanh| saturation index

// LDS layout (tables low: gathers fold base into 16-bit ds offset-imm)
#define L_SIGT  0             // u8[41152]
#define L_TANH  41152         // i8[10528]  |tanh| magnitude table
#define L_TANC  51680         // float[255] (1024 B slot, stride-4 = bank-spread)
#define L_HBUF  52704         // i8[2][HSLOT] = 4608 B
#define L_FCRED 57312         // int[128]
#define L_VOUT  57824         // float[16]
#define L_TOTAL 57888

#define XG_OFF  2129920       // xq_g base offset in workspace (after wsl)
#define XROW 48               // xq_g row stride (16B-aligned, zero-B spill)

// quad_perm DPP: broadcast even lane of each pair to both ([0,0,2,2]=0xA0),
// odd lane to both ([1,1,3,3]=0xF5). All lanes active in the time loop.
#define DPPQ(src, ctl) __builtin_amdgcn_update_dpp(0, (src), (ctl), 0xF, 0xF, true)

__device__ __forceinline__ int q8f(float v) {        // rint(clip(v*128, ±127))
    float t = fminf(fmaxf(v * 128.0f, -127.0f), 127.0f);
    return (int)rintf(t);
}

// fp32-faithful qp(x, a1=128, 8) on raw inputs
__device__ __forceinline__ int xq_f32(float xv) {
    float ax  = fabsf(xv);
    float d   = ax - 128.0f;
    float u   = ax - fabsf(d);
    float v   = u + 128.0f;
    float p   = 0.5f * v;
    float x01 = p * 0.0078125f;
    x01 = fminf(x01, 0.9921875f);
    int q = (int)rintf(x01 * 128.0f);
    return (xv < 0.0f) ? -q : q;
}

// ---------------- kernel 1: weight quant + B-frag pack, and x quant --------
// blocks [0,1040): wsl[o], o = ((((n*13+t)*4+G)*5+ch)*64 + lane)*2 + h
//   fragment byte p = 8h+jj of lane (q,c): k_in_chunk = 16q + 8h + jj
//   ch0 = x chunk (k<40, w_ih); ch1..4 = h chunks (kk = 64(ch-1)+k_in < 200)
// blocks [1040,2252): xq_g[t][row][48]: k<40 = q8(x), 40..47 = 0 (zero-B).
//   q=3 fragment reads spill 16B into the next row: weights for k_in 48..63
//   are zero, so the spilled bytes are never observed.
__global__ __launch_bounds__(256) void prep_wx(const float* __restrict__ w_ih,
                                               const float* __restrict__ w_hh,
                                               const float* __restrict__ x,
                                               unsigned long long* __restrict__ wsl,
                                               signed char* __restrict__ xg) {
    int bid = blockIdx.x;
    if (bid < 1040) {
        int o = bid * 256 + threadIdx.x;             // 0..266239
        int h = o & 1; int l = (o >> 1) & 63; int r = o >> 7;
        int ch = r % 5; r /= 5;
        int G = r & 3;  r >>= 2;
        int t = r % 13; int n = r / 13;
        int q = l >> 4, cc = l & 15;
        int colW = 16 * t + cc;
        unsigned long long pack = 0ull;
        if (colW < 200) {
            int col = G * 200 + colW;
            #pragma unroll
            for (int jj = 0; jj < 8; ++jj) {
                int k_in = 16 * q + 8 * h + jj;
                int v = 0;
                if (ch == 0) { if (k_in < 40) v = q8f(w_ih[(n * 40 + k_in) * 800 + col]); }
                else { int kk = 64 * (ch - 1) + k_in; if (kk < 200) v = q8f(w_hh[(n * 200 + kk) * 800 + col]); }
                pack |= (unsigned long long)((unsigned)v & 0xffu) << (8 * jj);
            }
        }
        wsl[o] = pack;
    } else {
        int i = (bid - 1040) * 256 + threadIdx.x;    // dword index
        if (i >= SEQn * 256 * 12) return;
        int t = i / 3072; int rem = i - t * 3072;
        int row = rem / 12; int k4 = rem - row * 12;
        unsigned pack = 0u;
        #pragma unroll
        for (int j = 0; j < 4; ++j) {
            int k = 4 * k4 + j;
            int v = 0;
            if (k < 40) v = xq_f32(x[(size_t)(t * 256 + row) * 40 + k]);
            pack |= ((unsigned)v & 0xffu) << (8 * j);
        }
        ((unsigned*)xg)[i] = pack;
    }
}

// ---------------- kernel 2: persistent LSTM ---------------------------------
__global__ __launch_bounds__(BLK) void lstm_k(const float* __restrict__ b_ih,
                                              const float* __restrict__ b_hh,
                                              const float* __restrict__ fw,
                                              const float* __restrict__ fb,
                                              const unsigned long long* __restrict__ wsl,
                                              const signed char* __restrict__ xg,
                                              float* __restrict__ out) {
    __shared__ __align__(16) unsigned char smem[L_TOTAL];
    unsigned char* sigt  = smem + L_SIGT;
    signed char*   tanh8 = (signed char*)(smem + L_TANH);
    float*         tanc  = (float*)(smem + L_TANC);
    signed char*   hbuf  = (signed char*)(smem + L_HBUF);
    int*           fcred = (int*)(smem + L_FCRED);
    float*         vout  = (float*)(smem + L_VOUT);

    const int tid  = threadIdx.x;
    const int n    = blockIdx.x >> 5;                // 0..7
    const int b0   = (blockIdx.x & 31) * 8;          // batch base (8 rows/WG)
    const int W    = tid >> 6;                       // wave 0..12, col-tile W
    const int lane = tid & 63;
    const int q    = lane >> 4;                      // quad
    const int c    = lane & 15;                      // A row idx / B col
    const int arow = c >> 1;                         // batch row held by A row c
    const int colW = 16 * W + c;
    const bool gok = (colW < 200);

    // ---- zero h buffers (h0 = 0; junk cols stay 0) ----
    for (int i = tid; i < (2 * HSLOT) / 4; i += BLK) ((int*)hbuf)[i] = 0;

    // ---- exact quant LUTs (proven R2-R19, verbatim) ----
    for (int i = tid; i < SIG_SZ; i += BLK) {
        float g = (float)(i - SIG_OFF) * (1.0f / 4096.0f);
        float s = 1.0f / (1.0f + expf(-g));
        float d = s - 1.0f;
        float u = s - fabsf(d);
        float p = 0.5f * (u + 1.0f);
        float t = fminf(fmaxf(p, -0.9921875f), 0.9921875f) * 128.0f;
        float rq = rintf(t);
        int qv = (int)rq;
        if (fabsf(t - rq) > 0.498f) {
            float s2 = 1.0f / (1.0f + (float)exp(-(double)g));
            float d2 = s2 - 1.0f;
            float u2 = s2 - fabsf(d2);
            float p2 = 0.5f * (u2 + 1.0f);
            qv = (int)rintf(fminf(fmaxf(p2, -0.9921875f), 0.9921875f) * 128.0f);
        }
        sigt[i] = (unsigned char)qv;
    }
    for (int i = tid; i < TMAX + 1; i += BLK) {      // |tanh| magnitude table
        float ag = (float)i * (1.0f / 4096.0f);
        float t0 = tanhf(ag);
        float d = t0 - 1.0f;
        float u = t0 - fabsf(d);
        float p = 0.5f * (u + 1.0f);
        float t = fminf(fmaxf(p, -0.9921875f), 0.9921875f) * 128.0f;
        float rq = rintf(t);
        int qv = (int)rq;
        if (fabsf(t - rq) > 0.498f) {
            float t2 = (float)tanh((double)ag);
            float d2 = t2 - 1.0f;
            float u2 = t2 - fabsf(d2);
            float p2 = 0.5f * (u2 + 1.0f);
            qv = (int)rintf(fminf(fmaxf(p2, -0.9921875f), 0.9921875f) * 128.0f);
        }
        tanh8[i] = (signed char)qv;
    }
    if (tid < 255) {                                 // float tanh(nc/32), idx = nc+127
        int nc = tid - 127;
        float t2 = (float)tanh((double)abs(nc) * (1.0 / 32.0));
        float d2 = t2 - 1.0f;
        float u2 = t2 - fabsf(d2);
        float p2 = 0.5f * (u2 + 1.0f);
        int qv = (int)rintf(fminf(fmaxf(p2, -0.9921875f), 0.9921875f) * 128.0f);
        tanc[tid] = (float)(nc < 0 ? -qv : qv);
    }

    // ---- register-resident K64 B fragments (coalesced 16B/lane loads) ----
    v4i Bv[4][5];
    {
        const unsigned long long* bb = wsl + (size_t)(n * 13 + W) * 4 * 5 * 128;
        #pragma unroll
        for (int G = 0; G < 4; ++G)
            #pragma unroll
            for (int ch = 0; ch < 5; ++ch) {
                unsigned long long lo = bb[(size_t)(G * 5 + ch) * 128 + lane * 2];
                unsigned long long hi2 = bb[(size_t)(G * 5 + ch) * 128 + lane * 2 + 1];
                union { unsigned long long u[2]; v4i v; } cv;
                cv.u[0] = lo; cv.u[1] = hi2;
                Bv[G][ch] = cv.v;
            }
    }

    // ---- bias per gate: sigmoid gates bake SIG_OFF; j-gate raw (sign path) --
    int bias[4];
    #pragma unroll
    for (int G = 0; G < 4; ++G) {
        int off = (G == 1) ? 0 : SIG_OFF;
        bias[G] = gok
            ? 32 * (q8f(b_ih[n * 800 + G * 200 + colW]) + q8f(b_hh[n * 800 + G * 200 + colW])) + off
            : off;
    }

    // lane item identity: rows 2q+rr (rr=0,1) from acc regs 2rr, col colW
    float cstf[2] = {0.f, 0.f};
    const signed char* xgv  = xg + (size_t)(b0 + arow) * XROW + 16 * q;  // + t*12288
    // paired h-read base: lane l fetches chunk m0+(l&1) segment of (arow, q)
    const signed char* hbPb = hbuf + arow * HST + 16 * q + 64 * (lane & 1);
    signed char* wrbb = hbuf + (2 * q) * HST + colW;
    const v4i zq = (v4i){0, 0, 0, 0};
    __syncthreads();                                 // LUTs + hbuf ready

    // ---- shadow for t=0: x-chunk MFMA + x32 + bias (elems 0,2 only) ----
    v4i a0[4];
    {
        v4i ax = *(const v4i*)(xgv);                 // global, L1-broadcast
        #pragma unroll
        for (int G = 0; G < 4; ++G) {
            v4i tx = __builtin_amdgcn_mfma_i32_16x16x64_i8(ax, Bv[G][0], zq, 0, 0, 0);
            tx[0] = tx[0] * 32 + bias[G];
            tx[2] = tx[2] * 32 + bias[G];
            a0[G] = tx;
        }
    }

// per-gate h-chain (4 dependent K64 MFMAs) and x-shadow for t+1
#define HCHAIN(G) \
    a0[G] = __builtin_amdgcn_mfma_i32_16x16x64_i8(ah1, Bv[G][1], a0[G], 0, 0, 0); \
    a0[G] = __builtin_amdgcn_mfma_i32_16x16x64_i8(ah2, Bv[G][2], a0[G], 0, 0, 0); \
    a0[G] = __builtin_amdgcn_mfma_i32_16x16x64_i8(ah3, Bv[G][3], a0[G], 0, 0, 0); \
    a0[G] = __builtin_amdgcn_mfma_i32_16x16x64_i8(ah4, Bv[G][4], a0[G], 0, 0, 0);
#define XSHAD(G) { \
    v4i tx = __builtin_amdgcn_mfma_i32_16x16x64_i8(xnext, Bv[G][0], zq, 0, 0, 0); \
    tx[0] = tx[0] * 32 + bias[G]; \
    tx[2] = tx[2] * 32 + bias[G]; \
    a0[G] = tx; }

    // ======================= time loop (1 barrier/step) =======================
    #pragma clang loop unroll(disable)
    for (int t = 0; t < SEQn; ++t) {
        // xq[t+1] prefetch BEFORE the barrier (R17-proven placement).
        // Clamped index: last step's shadow result is dead, no branch needed.
        int tn = (t < SEQn - 1) ? t + 1 : t;
        v4i xnext = *(const v4i*)(xgv + (size_t)tn * 12288);

        __syncthreads();                             // h(t) ready

        // ---- paired full-density h-reads + DPP fragment rebuild ----
        // read1: chunks 1|2 (even|odd lanes); read2: chunks 3|4.
        const signed char* hbP = hbPb + (t & 1) * HSLOT;
        v4i v12 = *(const v4i*)(hbP);
        v4i v34 = *(const v4i*)(hbP + 128);
        v4i ah1, ah2, ah3, ah4;
        #pragma unroll
        for (int dd = 0; dd < 4; ++dd) {
            ah1[dd] = DPPQ(v12[dd], 0xA0);           // even lane -> pair
            ah2[dd] = DPPQ(v12[dd], 0xF5);           // odd lane  -> pair
            ah3[dd] = DPPQ(v34[dd], 0xA0);
            ah4[dd] = DPPQ(v34[dd], 0xF5);
        }

        int qi[2], qf[2], qo[2], qj[2], gj_[2];

        // ---- gate 0 (i): chain -> extract -> gathers -> shadow ----
        HCHAIN(0)
        {
            int g0 = a0[0][0], g1 = a0[0][2];
            qi[0] = sigt[min(max(g0, 0), SIG_SZ - 1)];
            qi[1] = sigt[min(max(g1, 0), SIG_SZ - 1)];
        }
        XSHAD(0)

        // ---- gate 1 (j): tanh path ----
        HCHAIN(1)
        {
            gj_[0] = a0[1][0]; gj_[1] = a0[1][2];
            qj[0] = tanh8[min(abs(gj_[0]), TMAX)];
            qj[1] = tanh8[min(abs(gj_[1]), TMAX)];
        }
        XSHAD(1)

        // ---- gate 2 (f) ----
        HCHAIN(2)
        {
            int g0 = a0[2][0], g1 = a0[2][2];
            qf[0] = sigt[min(max(g0, 0), SIG_SZ - 1)];
            qf[1] = sigt[min(max(g1, 0), SIG_SZ - 1)];
        }
        XSHAD(2)

        // ---- gate 3 (o) ----
        HCHAIN(3)
        {
            int g0 = a0[3][0], g1 = a0[3][2];
            qo[0] = sigt[min(max(g0, 0), SIG_SZ - 1)];
            qo[1] = sigt[min(max(g1, 0), SIG_SZ - 1)];
        }
        XSHAD(3)

        // ---- float tail (bit-exact lattice chain) ----
        signed char* wrb = wrbb + ((t + 1) & 1) * HSLOT;
        float ncv[2]; int id2[2];
        #pragma unroll
        for (int rr = 0; rr < 2; ++rr) {
            int qjs = (gj_[rr] < 0) ? -qj[rr] : qj[rr];             // odd symmetry, bit-exact
            float gc = rintf(cstf[rr] * (float)qf[rr]);             // rint(cst*qf/128), exact
            float ai = rintf((float)qi[rr] * 0.0078125f * (float)qjs); // rint(qi*qj/128), exact
            float nc = rintf(fminf(fmaxf(fmaf(ai, 0.25f, gc), -127.0f), 127.0f));
            ncv[rr] = nc;
            id2[rr] = (int)(nc + 127.0f);
        }
        float ac[2];
        #pragma unroll
        for (int rr = 0; rr < 2; ++rr) ac[rr] = tanc[id2[rr]];      // level-2: bank-spread
        #pragma unroll
        for (int rr = 0; rr < 2; ++rr) {
            cstf[rr] = ncv[rr] * 0.0078125f;
            int nh = (int)rintf(ac[rr] * (float)qo[rr] * 0.001953125f); // rint(p/512), exact
            if (gok) wrb[rr * HST] = (signed char)nh;               // h(t+1), rows 2q+rr
        }
    }
#undef HCHAIN
#undef XSHAD
    __syncthreads();                                 // hT = h(101) in parity 1

    // ---- finFC: out_pre = (S + 32*qfb)/4096, then qp(.., fa2=16) ----
    const signed char* hT = hbuf + 1 * HSLOT;
    if (tid < 128) {
        int b = tid >> 4, oo = (tid >> 3) & 1, ch = tid & 7;
        int S = 0;
        for (int g2 = ch * 25; g2 < ch * 25 + 25; ++g2)
            S += (int)hT[b * HST + g2] * q8f(fw[(n * 200 + g2) * 2 + oo]);
        fcred[tid] = S;
    }
    __syncthreads();
    if (tid < 16) {
        int b = tid >> 1, oo = tid & 1;
        int S = 0;
        #pragma unroll
        for (int ch = 0; ch < 8; ++ch) S += fcred[b * 16 + oo * 8 + ch];
        S += 32 * q8f(fb[n * 2 + oo]);
        float f = fminf(fmaxf((float)S * 0.001953125f, -127.f), 127.f);
        int qo2 = (int)rintf(f);
        vout[tid] = (float)qo2 * 0.125f;
    }
    __syncthreads();
    if (tid < 16) {
        int b = tid >> 1, oo = tid & 1;
        int bg = b0 + b;
        if (n < 4) { if (oo == 0) out[bg * 12 + n] = vout[b * 2] + vout[b * 2 + 1]; }
        else out[bg * 12 + 4 + 2 * (n - 4) + oo] = vout[b * 2 + oo];
    }
}

// ---------------------------------------------------------------------------
extern "C" void kernel_launch(void* const* d_in, const int* in_sizes, int n_in,
                              void* d_out, int out_size, void* d_ws, size_t ws_size,
                              hipStream_t stream) {
    (void)in_sizes; (void)n_in; (void)out_size; (void)ws_size;
    const float* x    = (const float*)d_in[0];
    const float* w_ih = (const float*)d_in[1];
    const float* w_hh = (const float*)d_in[2];
    const float* b_ih = (const float*)d_in[3];
    const float* b_hh = (const float*)d_in[4];
    const float* fw   = (const float*)d_in[15];
    const float* fb   = (const float*)d_in[16];
    unsigned long long* wsl = (unsigned long long*)d_ws;   // 2,129,920 B
    signed char* xgq = (signed char*)d_ws + XG_OFF;        // 1,241,088 B

    prep_wx<<<2252, 256, 0, stream>>>(w_ih, w_hh, x, wsl, xgq);
    lstm_k<<<256, BLK, 0, stream>>>(b_ih, b_hh, fw, fb, wsl, xgq, (float*)d_out);
}

// Round 7
// 223.639 us; speedup vs baseline: 1.0271x; 1.0271x over previous
//
#include <hip/hip_runtime.h>
#include <cstdint>

// ===========================================================================
// KWS_LSTM_bmm — exact integer reformulation, fp32-faithful quant decisions.
// R21: revert R20's DPP dedup (regressed: broadcast made half-dense reads
//   cheap already; full-density pattern added bank conflicts + VALU movs).
//   New lever: RAW BARRIER (lgkmcnt-only). __syncthreads() emits
//   s_waitcnt vmcnt(0) lgkmcnt(0) + s_barrier; the vmcnt(0) drain forces
//   every wave to stall at the barrier on its in-flight xnext global load.
//   Cross-wave correctness only needs lgkmcnt(0) (LDS h-writes); xg is
//   read-only and xnext is same-wave-consumed (compiler auto-inserts the
//   vmcnt wait before XSHAD). So: asm lgkmcnt(0) + s_barrier builtin ->
//   the x load stays in flight across the barrier (counted-vmcnt, depth 1).
//   Kept: R19 gate-chain structure, pre-barrier x prefetch, fixed acc regs
//   0/2 (arow=c>>1), float tanc[255] (stride-4, bank-spread), 1 barrier/
//   step, 13 waves, 128 regs/wave.
// Exactness: every lattice chain bit-exact in fp32 (numerators < 2^24);
// sigmoid/tanh exact byte LUTs (fast fp32 + 0.498-margin fp64 fallback).
// ===========================================================================

typedef int v4i __attribute__((ext_vector_type(4)));

#define SEQn 101
#define BLK  832              // 13 waves
#define HST  288              // h row stride (2-way banks on b128 reads)
#define HSLOT 2304            // 8 rows
#define SIG_OFF 22720
#define SIG_SZ  41152         // sigmoid q-LUT (idx >= 41152 saturates to 127)
#define TMAX 10527            // |tanh| saturation index

// LDS layout (tables low: gathers fold base into 16-bit ds offset-imm)
#define L_SIGT  0             // u8[41152]
#define L_TANH  41152         // i8[10528]  |tanh| magnitude table
#define L_TANC  51680         // float[255] (1024 B slot, stride-4 = bank-spread)
#define L_HBUF  52704         // i8[2][HSLOT] = 4608 B
#define L_FCRED 57312         // int[128]
#define L_VOUT  57824         // float[16]
#define L_TOTAL 57888

#define XG_OFF  2129920       // xq_g base offset in workspace (after wsl)
#define XROW 48               // xq_g row stride (16B-aligned, zero-B spill)

__device__ __forceinline__ int q8f(float v) {        // rint(clip(v*128, ±127))
    float t = fminf(fmaxf(v * 128.0f, -127.0f), 127.0f);
    return (int)rintf(t);
}

// fp32-faithful qp(x, a1=128, 8) on raw inputs
__device__ __forceinline__ int xq_f32(float xv) {
    float ax  = fabsf(xv);
    float d   = ax - 128.0f;
    float u   = ax - fabsf(d);
    float v   = u + 128.0f;
    float p   = 0.5f * v;
    float x01 = p * 0.0078125f;
    x01 = fminf(x01, 0.9921875f);
    int q = (int)rintf(x01 * 128.0f);
    return (xv < 0.0f) ? -q : q;
}

// ---------------- kernel 1: weight quant + B-frag pack, and x quant --------
// blocks [0,1040): wsl[o], o = ((((n*13+t)*4+G)*5+ch)*64 + lane)*2 + h
//   fragment byte p = 8h+jj of lane (q,c): k_in_chunk = 16q + 8h + jj
//   ch0 = x chunk (k<40, w_ih); ch1..4 = h chunks (kk = 64(ch-1)+k_in < 200)
// blocks [1040,2252): xq_g[t][row][48]: k<40 = q8(x), 40..47 = 0 (zero-B).
//   q=3 fragment reads spill 16B into the next row: weights for k_in 48..63
//   are zero, so the spilled bytes are never observed.
__global__ __launch_bounds__(256) void prep_wx(const float* __restrict__ w_ih,
                                               const float* __restrict__ w_hh,
                                               const float* __restrict__ x,
                                               unsigned long long* __restrict__ wsl,
                                               signed char* __restrict__ xg) {
    int bid = blockIdx.x;
    if (bid < 1040) {
        int o = bid * 256 + threadIdx.x;             // 0..266239
        int h = o & 1; int l = (o >> 1) & 63; int r = o >> 7;
        int ch = r % 5; r /= 5;
        int G = r & 3;  r >>= 2;
        int t = r % 13; int n = r / 13;
        int q = l >> 4, cc = l & 15;
        int colW = 16 * t + cc;
        unsigned long long pack = 0ull;
        if (colW < 200) {
            int col = G * 200 + colW;
            #pragma unroll
            for (int jj = 0; jj < 8; ++jj) {
                int k_in = 16 * q + 8 * h + jj;
                int v = 0;
                if (ch == 0) { if (k_in < 40) v = q8f(w_ih[(n * 40 + k_in) * 800 + col]); }
                else { int kk = 64 * (ch - 1) + k_in; if (kk < 200) v = q8f(w_hh[(n * 200 + kk) * 800 + col]); }
                pack |= (unsigned long long)((unsigned)v & 0xffu) << (8 * jj);
            }
        }
        wsl[o] = pack;
    } else {
        int i = (bid - 1040) * 256 + threadIdx.x;    // dword index
        if (i >= SEQn * 256 * 12) return;
        int t = i / 3072; int rem = i - t * 3072;
        int row = rem / 12; int k4 = rem - row * 12;
        unsigned pack = 0u;
        #pragma unroll
        for (int j = 0; j < 4; ++j) {
            int k = 4 * k4 + j;
            int v = 0;
            if (k < 40) v = xq_f32(x[(size_t)(t * 256 + row) * 40 + k]);
            pack |= ((unsigned)v & 0xffu) << (8 * j);
        }
        ((unsigned*)xg)[i] = pack;
    }
}

// ---------------- kernel 2: persistent LSTM ---------------------------------
__global__ __launch_bounds__(BLK) void lstm_k(const float* __restrict__ b_ih,
                                              const float* __restrict__ b_hh,
                                              const float* __restrict__ fw,
                                              const float* __restrict__ fb,
                                              const unsigned long long* __restrict__ wsl,
                                              const signed char* __restrict__ xg,
                                              float* __restrict__ out) {
    __shared__ __align__(16) unsigned char smem[L_TOTAL];
    unsigned char* sigt  = smem + L_SIGT;
    signed char*   tanh8 = (signed char*)(smem + L_TANH);
    float*         tanc  = (float*)(smem + L_TANC);
    signed char*   hbuf  = (signed char*)(smem + L_HBUF);
    int*           fcred = (int*)(smem + L_FCRED);
    float*         vout  = (float*)(smem + L_VOUT);

    const int tid  = threadIdx.x;
    const int n    = blockIdx.x >> 5;                // 0..7
    const int b0   = (blockIdx.x & 31) * 8;          // batch base (8 rows/WG)
    const int W    = tid >> 6;                       // wave 0..12, col-tile W
    const int lane = tid & 63;
    const int q    = lane >> 4;                      // quad
    const int c    = lane & 15;                      // A row idx / B col
    const int arow = c >> 1;                         // batch row held by A row c
    const int colW = 16 * W + c;
    const bool gok = (colW < 200);

    // ---- zero h buffers (h0 = 0; junk cols stay 0) ----
    for (int i = tid; i < (2 * HSLOT) / 4; i += BLK) ((int*)hbuf)[i] = 0;

    // ---- exact quant LUTs (proven R2-R20, verbatim) ----
    for (int i = tid; i < SIG_SZ; i += BLK) {
        float g = (float)(i - SIG_OFF) * (1.0f / 4096.0f);
        float s = 1.0f / (1.0f + expf(-g));
        float d = s - 1.0f;
        float u = s - fabsf(d);
        float p = 0.5f * (u + 1.0f);
        float t = fminf(fmaxf(p, -0.9921875f), 0.9921875f) * 128.0f;
        float rq = rintf(t);
        int qv = (int)rq;
        if (fabsf(t - rq) > 0.498f) {
            float s2 = 1.0f / (1.0f + (float)exp(-(double)g));
            float d2 = s2 - 1.0f;
            float u2 = s2 - fabsf(d2);
            float p2 = 0.5f * (u2 + 1.0f);
            qv = (int)rintf(fminf(fmaxf(p2, -0.9921875f), 0.9921875f) * 128.0f);
        }
        sigt[i] = (unsigned char)qv;
    }
    for (int i = tid; i < TMAX + 1; i += BLK) {      // |tanh| magnitude table
        float ag = (float)i * (1.0f / 4096.0f);
        float t0 = tanhf(ag);
        float d = t0 - 1.0f;
        float u = t0 - fabsf(d);
        float p = 0.5f * (u + 1.0f);
        float t = fminf(fmaxf(p, -0.9921875f), 0.9921875f) * 128.0f;
        float rq = rintf(t);
        int qv = (int)rq;
        if (fabsf(t - rq) > 0.498f) {
            float t2 = (float)tanh((double)ag);
            float d2 = t2 - 1.0f;
            float u2 = t2 - fabsf(d2);
            float p2 = 0.5f * (u2 + 1.0f);
            qv = (int)rintf(fminf(fmaxf(p2, -0.9921875f), 0.9921875f) * 128.0f);
        }
        tanh8[i] = (signed char)qv;
    }
    if (tid < 255) {                                 // float tanh(nc/32), idx = nc+127
        int nc = tid - 127;
        float t2 = (float)tanh((double)abs(nc) * (1.0 / 32.0));
        float d2 = t2 - 1.0f;
        float u2 = t2 - fabsf(d2);
        float p2 = 0.5f * (u2 + 1.0f);
        int qv = (int)rintf(fminf(fmaxf(p2, -0.9921875f), 0.9921875f) * 128.0f);
        tanc[tid] = (float)(nc < 0 ? -qv : qv);
    }

    // ---- register-resident K64 B fragments (coalesced 16B/lane loads) ----
    v4i Bv[4][5];
    {
        const unsigned long long* bb = wsl + (size_t)(n * 13 + W) * 4 * 5 * 128;
        #pragma unroll
        for (int G = 0; G < 4; ++G)
            #pragma unroll
            for (int ch = 0; ch < 5; ++ch) {
                unsigned long long lo = bb[(size_t)(G * 5 + ch) * 128 + lane * 2];
                unsigned long long hi2 = bb[(size_t)(G * 5 + ch) * 128 + lane * 2 + 1];
                union { unsigned long long u[2]; v4i v; } cv;
                cv.u[0] = lo; cv.u[1] = hi2;
                Bv[G][ch] = cv.v;
            }
    }

    // ---- bias per gate: sigmoid gates bake SIG_OFF; j-gate raw (sign path) --
    int bias[4];
    #pragma unroll
    for (int G = 0; G < 4; ++G) {
        int off = (G == 1) ? 0 : SIG_OFF;
        bias[G] = gok
            ? 32 * (q8f(b_ih[n * 800 + G * 200 + colW]) + q8f(b_hh[n * 800 + G * 200 + colW])) + off
            : off;
    }

    // lane item identity: rows 2q+rr (rr=0,1) from acc regs 2rr, col colW
    float cstf[2] = {0.f, 0.f};
    const signed char* xgv  = xg + (size_t)(b0 + arow) * XROW + 16 * q;  // + t*12288
    const signed char* hbRb = hbuf + arow * HST + 16 * q;
    signed char* wrbb = hbuf + (2 * q) * HST + colW;
    const v4i zq = (v4i){0, 0, 0, 0};
    __syncthreads();                                 // LUTs + hbuf ready (full sync)

    // ---- shadow for t=0: x-chunk MFMA + x32 + bias (elems 0,2 only) ----
    v4i a0[4];
    {
        v4i ax = *(const v4i*)(xgv);                 // global, L1-broadcast
        #pragma unroll
        for (int G = 0; G < 4; ++G) {
            v4i tx = __builtin_amdgcn_mfma_i32_16x16x64_i8(ax, Bv[G][0], zq, 0, 0, 0);
            tx[0] = tx[0] * 32 + bias[G];
            tx[2] = tx[2] * 32 + bias[G];
            a0[G] = tx;
        }
    }

// per-gate h-chain (4 dependent K64 MFMAs) and x-shadow for t+1
#define HCHAIN(G) \
    a0[G] = __builtin_amdgcn_mfma_i32_16x16x64_i8(ah1, Bv[G][1], a0[G], 0, 0, 0); \
    a0[G] = __builtin_amdgcn_mfma_i32_16x16x64_i8(ah2, Bv[G][2], a0[G], 0, 0, 0); \
    a0[G] = __builtin_amdgcn_mfma_i32_16x16x64_i8(ah3, Bv[G][3], a0[G], 0, 0, 0); \
    a0[G] = __builtin_amdgcn_mfma_i32_16x16x64_i8(ah4, Bv[G][4], a0[G], 0, 0, 0);
#define XSHAD(G) { \
    v4i tx = __builtin_amdgcn_mfma_i32_16x16x64_i8(xnext, Bv[G][0], zq, 0, 0, 0); \
    tx[0] = tx[0] * 32 + bias[G]; \
    tx[2] = tx[2] * 32 + bias[G]; \
    a0[G] = tx; }

    // ======================= time loop (1 barrier/step) =======================
    #pragma clang loop unroll(disable)
    for (int t = 0; t < SEQn; ++t) {
        // xq[t+1] prefetch BEFORE the barrier. With the raw lgkm-only
        // barrier below, this load stays in flight ACROSS the barrier
        // (counted-vmcnt depth 1); the compiler inserts the vmcnt wait
        // only at XSHAD's use, covered by h-MFMAs + gathers.
        int tn = (t < SEQn - 1) ? t + 1 : t;
        v4i xnext = *(const v4i*)(xgv + (size_t)tn * 12288);

        // ---- raw barrier: drain LDS only (h-writes), NOT vmcnt ----
        // Cross-wave dep is only the ds_write h-exchange; xg is read-only.
        asm volatile("s_waitcnt lgkmcnt(0)" ::: "memory");
        __builtin_amdgcn_s_barrier();                // h(t) ready

        // all 4 h-chunk fragments up front (independent b128 reads;
        // lane pairs share addresses -> broadcast, conflict-free)
        const signed char* hbR = hbRb + (t & 1) * HSLOT;
        v4i ah1 = *(const v4i*)(hbR);
        v4i ah2 = *(const v4i*)(hbR + 64);
        v4i ah3 = *(const v4i*)(hbR + 128);
        v4i ah4 = *(const v4i*)(hbR + 192);

        int qi[2], qf[2], qo[2], qj[2], gj_[2];

        // ---- gate 0 (i): chain -> extract -> gathers -> shadow ----
        HCHAIN(0)
        {
            int g0 = a0[0][0], g1 = a0[0][2];
            qi[0] = sigt[min(max(g0, 0), SIG_SZ - 1)];
            qi[1] = sigt[min(max(g1, 0), SIG_SZ - 1)];
        }
        XSHAD(0)

        // ---- gate 1 (j): tanh path ----
        HCHAIN(1)
        {
            gj_[0] = a0[1][0]; gj_[1] = a0[1][2];
            qj[0] = tanh8[min(abs(gj_[0]), TMAX)];
            qj[1] = tanh8[min(abs(gj_[1]), TMAX)];
        }
        XSHAD(1)

        // ---- gate 2 (f) ----
        HCHAIN(2)
        {
            int g0 = a0[2][0], g1 = a0[2][2];
            qf[0] = sigt[min(max(g0, 0), SIG_SZ - 1)];
            qf[1] = sigt[min(max(g1, 0), SIG_SZ - 1)];
        }
        XSHAD(2)

        // ---- gate 3 (o) ----
        HCHAIN(3)
        {
            int g0 = a0[3][0], g1 = a0[3][2];
            qo[0] = sigt[min(max(g0, 0), SIG_SZ - 1)];
            qo[1] = sigt[min(max(g1, 0), SIG_SZ - 1)];
        }
        XSHAD(3)

        // ---- float tail (bit-exact lattice chain) ----
        signed char* wrb = wrbb + ((t + 1) & 1) * HSLOT;
        float ncv[2]; int id2[2];
        #pragma unroll
        for (int rr = 0; rr < 2; ++rr) {
            int qjs = (gj_[rr] < 0) ? -qj[rr] : qj[rr];             // odd symmetry, bit-exact
            float gc = rintf(cstf[rr] * (float)qf[rr]);             // rint(cst*qf/128), exact
            float ai = rintf((float)qi[rr] * 0.0078125f * (float)qjs); // rint(qi*qj/128), exact
            float nc = rintf(fminf(fmaxf(fmaf(ai, 0.25f, gc), -127.0f), 127.0f));
            ncv[rr] = nc;
            id2[rr] = (int)(nc + 127.0f);
        }
        float ac[2];
        #pragma unroll
        for (int rr = 0; rr < 2; ++rr) ac[rr] = tanc[id2[rr]];      // level-2: bank-spread
        #pragma unroll
        for (int rr = 0; rr < 2; ++rr) {
            cstf[rr] = ncv[rr] * 0.0078125f;
            int nh = (int)rintf(ac[rr] * (float)qo[rr] * 0.001953125f); // rint(p/512), exact
            if (gok) wrb[rr * HST] = (signed char)nh;               // h(t+1), rows 2q+rr
        }
    }
#undef HCHAIN
#undef XSHAD
    __syncthreads();                                 // hT = h(101) in parity 1

    // ---- finFC: out_pre = (S + 32*qfb)/4096, then qp(.., fa2=16) ----
    const signed char* hT = hbuf + 1 * HSLOT;
    if (tid < 128) {
        int b = tid >> 4, oo = (tid >> 3) & 1, ch = tid & 7;
        int S = 0;
        for (int g2 = ch * 25; g2 < ch * 25 + 25; ++g2)
            S += (int)hT[b * HST + g2] * q8f(fw[(n * 200 + g2) * 2 + oo]);
        fcred[tid] = S;
    }
    __syncthreads();
    if (tid < 16) {
        int b = tid >> 1, oo = tid & 1;
        int S = 0;
        #pragma unroll
        for (int ch = 0; ch < 8; ++ch) S += fcred[b * 16 + oo * 8 + ch];
        S += 32 * q8f(fb[n * 2 + oo]);
        float f = fminf(fmaxf((float)S * 0.001953125f, -127.f), 127.f);
        int qo2 = (int)rintf(f);
        vout[tid] = (float)qo2 * 0.125f;
    }
    __syncthreads();
    if (tid < 16) {
        int b = tid >> 1, oo = tid & 1;
        int bg = b0 + b;
        if (n < 4) { if (oo == 0) out[bg * 12 + n] = vout[b * 2] + vout[b * 2 + 1]; }
        else out[bg * 12 + 4 + 2 * (n - 4) + oo] = vout[b * 2 + oo];
    }
}

// ---------------------------------------------------------------------------
extern "C" void kernel_launch(void* const* d_in, const int* in_sizes, int n_in,
                              void* d_out, int out_size, void* d_ws, size_t ws_size,
                              hipStream_t stream) {
    (void)in_sizes; (void)n_in; (void)out_size; (void)ws_size;
    const float* x    = (const float*)d_in[0];
    const float* w_ih = (const float*)d_in[1];
    const float* w_hh = (const float*)d_in[2];
    const float* b_ih = (const float*)d_in[3];
    const float* b_hh = (const float*)d_in[4];
    const float* fw   = (const float*)d_in[15];
    const float* fb   = (const float*)d_in[16];
    unsigned long long* wsl = (unsigned long long*)d_ws;   // 2,129,920 B
    signed char* xgq = (signed char*)d_ws + XG_OFF;        // 1,241,088 B

    prep_wx<<<2252, 256, 0, stream>>>(w_ih, w_hh, x, wsl, xgq);
    lstm_k<<<256, BLK, 0, stream>>>(b_ih, b_hh, fw, fb, wsl, xgq, (float*)d_out);
}